// Round 2
// baseline (2825.216 us; speedup 1.0000x reference)
//
#include <hip/hip_runtime.h>
#include <hip/hip_bf16.h>

// Sizes (fixed): T=512 tokens, D=256 embed, L=256 lstm, H=512 hidden. 4L=1024.

typedef _Float16 h2v __attribute__((ext_vector_type(2)));
typedef unsigned int u32x8 __attribute__((ext_vector_type(8)));

#define BC(x) __builtin_bit_cast(h2v, (x))

__device__ __forceinline__ float fdot2f(h2v a, h2v b, float c) {
#if __has_builtin(__builtin_amdgcn_fdot2)
    return __builtin_amdgcn_fdot2(a, b, c, false);
#else
    return c + (float)a[0] * (float)b[0] + (float)a[1] * (float)b[1];
#endif
}

// ---------------------------------------------------------------------------
// prep_u: U [256 x 1024] f32 row-major -> packed half2 per (k-pair, col)
// Uf[k2*1024 + col] = (U[2k2][col], U[2k2+1][col]) as 2xf16 in a uint
// ---------------------------------------------------------------------------
__global__ __launch_bounds__(256) void prep_u(const float* __restrict__ U,
                                              unsigned int* __restrict__ Uf) {
    int idx = blockIdx.x * 256 + threadIdx.x;  // < 131072
    int k2 = idx >> 10, col = idx & 1023;
    union { _Float16 h[2]; unsigned int u; } p;
    p.h[0] = (_Float16)U[(2 * k2) * 1024 + col];
    p.h[1] = (_Float16)U[(2 * k2 + 1) * 1024 + col];
    Uf[idx] = p.u;
}

// ---------------------------------------------------------------------------
// Generic f32 GEMM: C[M,N] = opA(A)[M,K] @ B[K,N] + bias[N]
// ---------------------------------------------------------------------------
__global__ __launch_bounds__(256) void gemm_bias(const float* __restrict__ A,
                                                 const float* __restrict__ B,
                                                 const float* __restrict__ bias,
                                                 float* __restrict__ C,
                                                 int M, int N, int K, int revA) {
    __shared__ float sA[16][65];
    __shared__ float sB[16][65];
    int tid = threadIdx.x;
    int bm = blockIdx.y * 64, bn = blockIdx.x * 64;
    int tx = tid & 15, ty = tid >> 4;
    float acc[4][4] = {};
    for (int k0 = 0; k0 < K; k0 += 16) {
#pragma unroll
        for (int l = 0; l < 4; l++) {
            int flat = tid + 256 * l;
            int ml = flat >> 4, kk = flat & 15;
            int row = bm + ml;
            if (revA) row = M - 1 - row;
            sA[kk][ml] = A[row * K + k0 + kk];
        }
#pragma unroll
        for (int l = 0; l < 4; l++) {
            int flat = tid + 256 * l;
            int kk = flat >> 6, nl = flat & 63;
            sB[kk][nl] = B[(k0 + kk) * N + bn + nl];
        }
        __syncthreads();
#pragma unroll
        for (int kk = 0; kk < 16; kk++) {
            float a[4], b[4];
#pragma unroll
            for (int i = 0; i < 4; i++) a[i] = sA[kk][ty + 16 * i];
#pragma unroll
            for (int j = 0; j < 4; j++) b[j] = sB[kk][tx + 16 * j];
#pragma unroll
            for (int i = 0; i < 4; i++)
#pragma unroll
                for (int j = 0; j < 4; j++) acc[i][j] += a[i] * b[j];
        }
        __syncthreads();
    }
#pragma unroll
    for (int i = 0; i < 4; i++) {
        int r = bm + ty + 16 * i;
#pragma unroll
        for (int j = 0; j < 4; j++) {
            int cidx = bn + tx + 16 * j;
            float bv = bias ? bias[cidx] : 0.f;
            C[r * N + cidx] = acc[i][j] + bv;
        }
    }
}

// ---------------------------------------------------------------------------
// lstm_two: 2 blocks (fwd, bwd), 1024 threads, 1 block/CU.
//
// HW-budget post-mortem (rounds 0-1 counters): the backend's VGPR budget for
// this kernel is 128 and amdgpu_waves_per_eu(2,2) does NOT raise it to 256 —
// both the remat version and the asm-pinned version compiled to
// VGPR_Count=128 with identical 1172us (pin => spill-to-scratch; scratch is
// L2-resident so per-step reload traffic is invisible in FETCH_SIZE). The
// 512-thread/192-U-reg design never existed on hardware; it ran as an
// L2-restream loop (~71 B/cyc/CU fill path, 5.5K cyc/step).
//
// Redesign WITHIN the 128-reg budget: 1024 threads (16 waves = 4 waves/EU,
// the budget's natural occupancy), one column per thread => U slice per
// thread halves to 96 uints (12 x u32x8) + ~20 working regs < 128. Remaining
// 32 k-pairs stay in LDS k-major (lane-consecutive b32, conflict-free).
// Nothing streams from L2 in the step loop. Two acc chains (even/odd chunks)
// keep dot2 dependency latency covered at 4 waves/EU.
// ---------------------------------------------------------------------------
#define KLDS 32
#define KREG 96

// constant-index select across the twelve 8-wide vectors; folds at -O3
#define UA(r) ((r) < 8 ? q0[(r) & 7] : (r) < 16 ? q1[(r) & 7] : (r) < 24 ? q2[(r) & 7] : \
               (r) < 32 ? q3[(r) & 7] : (r) < 40 ? q4[(r) & 7] : (r) < 48 ? q5[(r) & 7] : \
               (r) < 56 ? q6[(r) & 7] : (r) < 64 ? q7[(r) & 7] : (r) < 72 ? q8[(r) & 7] : \
               (r) < 80 ? q9[(r) & 7] : (r) < 88 ? q10[(r) & 7] : q11[(r) & 7])

#define LOADQ(qi, va)                                                   \
    do {                                                                \
        _Pragma("unroll") for (int j = 0; j < 8; j++) {                 \
            va[j] = U[(KLDS + 8 * (qi) + j) * 1024 + t];                \
        }                                                               \
    } while (0)

__global__ __attribute__((amdgpu_flat_work_group_size(1024, 1024),
                          amdgpu_waves_per_eu(4, 4)))
void lstm_two(
        const unsigned int* __restrict__ Ua, const unsigned int* __restrict__ Ub,
        const float* __restrict__ Pa, const float* __restrict__ Pb,
        float* __restrict__ Oa, float* __restrict__ Ob) {
    const unsigned int* U = blockIdx.x ? Ub : Ua;
    const float* P = blockIdx.x ? Pb : Pa;
    float* O = blockIdx.x ? Ob : Oa;

    __shared__ unsigned int sU[KLDS * 1024];        // 131072 B, k-major
    __shared__ __align__(16) _Float16 sH[256];      // 512 B
    __shared__ float sZ[1024];                      // 4096 B

    int t = threadIdx.x;  // 0..1023, owns column t

    // stage LDS-resident k-pairs of U (k-major: sU[kp*1024 + col])
    for (int i = t; i < KLDS * 1024; i += 1024) sU[i] = U[i];

    // register-resident k-pairs [KLDS, KLDS+96) for this thread's column:
    // 12 x 8-wide SSA vectors = 96 VGPRs. Fits the 128 budget with room for
    // the ~20-reg working set, so no spill and no remat pressure.
    u32x8 q0, q1, q2, q3, q4, q5, q6, q7, q8, q9, q10, q11;
    LOADQ(0, q0);   LOADQ(1, q1);   LOADQ(2, q2);   LOADQ(3, q3);
    LOADQ(4, q4);   LOADQ(5, q5);   LOADQ(6, q6);   LOADQ(7, q7);
    LOADQ(8, q8);   LOADQ(9, q9);   LOADQ(10, q10); LOADQ(11, q11);

    // insurance against rematerialization of the loop-invariant loads
    asm volatile(""
                 : "+v"(q0), "+v"(q1), "+v"(q2), "+v"(q3), "+v"(q4), "+v"(q5),
                   "+v"(q6), "+v"(q7), "+v"(q8), "+v"(q9), "+v"(q10), "+v"(q11));

    float c = 0.f;
    if (t < 256) sH[t] = (_Float16)0.f;
    __syncthreads();

    const uint4* hp4 = (const uint4*)sH;  // 32 chunks x (4 h2v) = 256 h
    float pc = P[t];
    for (int step = 0; step < 512; step++) {
        float pn = pc;
        if (step < 511) pn = P[(step + 1) * 1024 + t];
        float acc0 = pc, acc1 = 0.f;  // two chains to cover dot2 latency

        // k-pairs 0..31 from LDS: h via b128 broadcast, U via lane-consecutive
        // b32 (conflict-free)
#pragma unroll
        for (int cch = 0; cch < 8; cch++) {
            uint4 hc = hp4[cch];
            const unsigned int* su = &sU[(4 * cch) * 1024 + t];
            acc0 = fdot2f(BC(hc.x), BC(su[0]), acc0);
            acc1 = fdot2f(BC(hc.y), BC(su[1024]), acc1);
            acc0 = fdot2f(BC(hc.z), BC(su[2048]), acc0);
            acc1 = fdot2f(BC(hc.w), BC(su[3072]), acc1);
        }
        // k-pairs 32..127 from registers
#pragma unroll
        for (int cch = 0; cch < 24; cch++) {
            uint4 hc = hp4[8 + cch];
            const int r0 = 4 * cch;
            acc0 = fdot2f(BC(hc.x), BC(UA(r0 + 0)), acc0);
            acc1 = fdot2f(BC(hc.y), BC(UA(r0 + 1)), acc1);
            acc0 = fdot2f(BC(hc.z), BC(UA(r0 + 2)), acc0);
            acc1 = fdot2f(BC(hc.w), BC(UA(r0 + 3)), acc1);
        }
        sZ[t] = acc0 + acc1;
        __syncthreads();
        if (t < 256) {
            float zi = sZ[t], zf = sZ[256 + t], zg = sZ[512 + t], zo = sZ[768 + t];
            float ig = 1.f / (1.f + __expf(-zi));
            float fg = 1.f / (1.f + __expf(-zf));
            float gg = 1.f - 2.f / (1.f + __expf(2.f * zg));   // tanh
            float og = 1.f / (1.f + __expf(-zo));
            c = fg * c + ig * gg;
            float h = og * (1.f - 2.f / (1.f + __expf(2.f * c)));
            O[step * 256 + t] = h;
            sH[t] = (_Float16)h;
        }
        __syncthreads();
        pc = pn;
    }
}

// ---------------------------------------------------------------------------
// concat: V[t][0:256] = F[t], V[t][256:512] = Bk[511-t]
// ---------------------------------------------------------------------------
__global__ __launch_bounds__(256) void concat_k(const float* __restrict__ F,
                                                const float* __restrict__ Bk,
                                                float* __restrict__ V) {
    int idx = blockIdx.x * 256 + threadIdx.x;  // < 262144
    int t = idx >> 9, d = idx & 511;
    V[idx] = (d < 256) ? F[t * 256 + d] : Bk[(511 - t) * 256 + d - 256];
}

// ---------------------------------------------------------------------------
// head: S[i][j] = sum_h tanh(HF[i][h] + MF[j][h]) * w[h] + outBias
// ---------------------------------------------------------------------------
__global__ __launch_bounds__(256) void head_kernel(const float* __restrict__ HF,
                                                   const float* __restrict__ MF,
                                                   const float* __restrict__ w,
                                                   const float* __restrict__ outb,
                                                   float* __restrict__ S) {
    int i = blockIdx.x;
    __shared__ float sHF[512], sW[512];
    int tid = threadIdx.x;
    sHF[tid] = HF[i * 512 + tid];
    sHF[tid + 256] = HF[i * 512 + 256 + tid];
    sW[tid] = w[tid];
    sW[tid + 256] = w[tid + 256];
    __syncthreads();
    int lane = tid & 63, wv = tid >> 6;
    float ob = outb[0];
    for (int j = wv; j < 512; j += 4) {
        const float* mf = MF + j * 512;
        float acc = 0.f;
#pragma unroll
        for (int r = 0; r < 8; r++) {
            int h = lane + 64 * r;
            float x = sHF[h] + mf[h];
            acc += sW[h] * (1.f - 2.f / (1.f + __expf(2.f * x)));
        }
#pragma unroll
        for (int off = 32; off; off >>= 1) acc += __shfl_down(acc, off);
        if (lane == 0) S[i * 512 + j] = acc + ob;
    }
}

// ---------------------------------------------------------------------------
extern "C" void kernel_launch(void* const* d_in, const int* in_sizes, int n_in,
                              void* d_out, int out_size, void* d_ws, size_t ws_size,
                              hipStream_t stream) {
    const float* emb      = (const float*)d_in[0];
    const float* W_f1     = (const float*)d_in[1];
    const float* U_f1     = (const float*)d_in[2];
    const float* b_f1     = (const float*)d_in[3];
    const float* W_b1     = (const float*)d_in[4];
    const float* U_b1     = (const float*)d_in[5];
    const float* b_b1     = (const float*)d_in[6];
    const float* W_f2     = (const float*)d_in[7];
    const float* U_f2     = (const float*)d_in[8];
    const float* b_f2     = (const float*)d_in[9];
    const float* W_b2     = (const float*)d_in[10];
    const float* U_b2     = (const float*)d_in[11];
    const float* b_b2     = (const float*)d_in[12];
    const float* FOH      = (const float*)d_in[13];
    const float* FOM      = (const float*)d_in[14];
    const float* hidBias  = (const float*)d_in[15];
    const float* outLayer = (const float*)d_in[16];
    const float* outBias  = (const float*)d_in[17];
    float* out = (float*)d_out;

    // workspace carve (16 MB total)
    unsigned int* uf = (unsigned int*)d_ws;          // 4 x 131072 uints = 2MB
    unsigned int* uf_f1 = uf;
    unsigned int* uf_b1 = uf + 131072;
    unsigned int* uf_f2 = uf + 262144;
    unsigned int* uf_b2 = uf + 393216;
    float* f = (float*)d_ws + 524288;
    float* P1f = f;                 // 512x1024
    float* P1b = f + 524288;
    float* P2f = f + 1048576;
    float* P2b = f + 1572864;
    float* rf1 = f + 2097152;       // 512x256
    float* rb1 = f + 2228224;
    float* rf2 = f + 2359296;
    float* rb2 = f + 2490368;
    float* v    = f + 2621440;      // 512x512
    float* hcat = f + 2883584;
    float* HFb  = f + 3145728;      // 512x512 (includes hidBias)
    float* MFb  = f + 3407872;

    prep_u<<<512, 256, 0, stream>>>(U_f1, uf_f1);
    prep_u<<<512, 256, 0, stream>>>(U_b1, uf_b1);
    prep_u<<<512, 256, 0, stream>>>(U_f2, uf_f2);
    prep_u<<<512, 256, 0, stream>>>(U_b2, uf_b2);

    dim3 g1(1024 / 64, 512 / 64);
    gemm_bias<<<g1, 256, 0, stream>>>(emb, W_f1, b_f1, P1f, 512, 1024, 256, 0);
    gemm_bias<<<g1, 256, 0, stream>>>(emb, W_b1, b_b1, P1b, 512, 1024, 256, 1);

    lstm_two<<<2, 1024, 0, stream>>>(uf_f1, uf_b1, P1f, P1b, rf1, rb1);

    concat_k<<<1024, 256, 0, stream>>>(rf1, rb1, v);

    gemm_bias<<<g1, 256, 0, stream>>>(v, W_f2, b_f2, P2f, 512, 1024, 512, 0);
    gemm_bias<<<g1, 256, 0, stream>>>(v, W_b2, b_b2, P2b, 512, 1024, 512, 1);

    lstm_two<<<2, 1024, 0, stream>>>(uf_f2, uf_b2, P2f, P2b, rf2, rb2);

    concat_k<<<1024, 256, 0, stream>>>(rf2, rb2, hcat);

    dim3 g2(512 / 64, 512 / 64);
    gemm_bias<<<g2, 256, 0, stream>>>(hcat, FOH, hidBias, HFb, 512, 512, 512, 0);
    gemm_bias<<<g2, 256, 0, stream>>>(hcat, FOM, nullptr, MFb, 512, 512, 512, 0);

    head_kernel<<<512, 256, 0, stream>>>(HFb, MFb, outLayer, outBias, out);
}

// Round 3
// 2822.008 us; speedup vs baseline: 1.0011x; 1.0011x over previous
//
#include <hip/hip_runtime.h>
#include <hip/hip_bf16.h>

// Sizes (fixed): T=512 tokens, D=256 embed, L=256 lstm, H=512 hidden. 4L=1024.

typedef _Float16 h2v __attribute__((ext_vector_type(2)));
typedef unsigned int u32x8 __attribute__((ext_vector_type(8)));

#define BC(x) __builtin_bit_cast(h2v, (x))

__device__ __forceinline__ float fdot2f(h2v a, h2v b, float c) {
#if __has_builtin(__builtin_amdgcn_fdot2)
    return __builtin_amdgcn_fdot2(a, b, c, false);
#else
    return c + (float)a[0] * (float)b[0] + (float)a[1] * (float)b[1];
#endif
}

// ---------------------------------------------------------------------------
// prep_u: U [256 x 1024] f32 row-major -> packed half2 per (k-pair, col)
// Uf[k2*1024 + col] = (U[2k2][col], U[2k2+1][col]) as 2xf16 in a uint
// ---------------------------------------------------------------------------
__global__ __launch_bounds__(256) void prep_u(const float* __restrict__ U,
                                              unsigned int* __restrict__ Uf) {
    int idx = blockIdx.x * 256 + threadIdx.x;  // < 131072
    int k2 = idx >> 10, col = idx & 1023;
    union { _Float16 h[2]; unsigned int u; } p;
    p.h[0] = (_Float16)U[(2 * k2) * 1024 + col];
    p.h[1] = (_Float16)U[(2 * k2 + 1) * 1024 + col];
    Uf[idx] = p.u;
}

// ---------------------------------------------------------------------------
// Generic f32 GEMM: C[M,N] = opA(A)[M,K] @ B[K,N] + bias[N]
// ---------------------------------------------------------------------------
__global__ __launch_bounds__(256) void gemm_bias(const float* __restrict__ A,
                                                 const float* __restrict__ B,
                                                 const float* __restrict__ bias,
                                                 float* __restrict__ C,
                                                 int M, int N, int K, int revA) {
    __shared__ float sA[16][65];
    __shared__ float sB[16][65];
    int tid = threadIdx.x;
    int bm = blockIdx.y * 64, bn = blockIdx.x * 64;
    int tx = tid & 15, ty = tid >> 4;
    float acc[4][4] = {};
    for (int k0 = 0; k0 < K; k0 += 16) {
#pragma unroll
        for (int l = 0; l < 4; l++) {
            int flat = tid + 256 * l;
            int ml = flat >> 4, kk = flat & 15;
            int row = bm + ml;
            if (revA) row = M - 1 - row;
            sA[kk][ml] = A[row * K + k0 + kk];
        }
#pragma unroll
        for (int l = 0; l < 4; l++) {
            int flat = tid + 256 * l;
            int kk = flat >> 6, nl = flat & 63;
            sB[kk][nl] = B[(k0 + kk) * N + bn + nl];
        }
        __syncthreads();
#pragma unroll
        for (int kk = 0; kk < 16; kk++) {
            float a[4], b[4];
#pragma unroll
            for (int i = 0; i < 4; i++) a[i] = sA[kk][ty + 16 * i];
#pragma unroll
            for (int j = 0; j < 4; j++) b[j] = sB[kk][tx + 16 * j];
#pragma unroll
            for (int i = 0; i < 4; i++)
#pragma unroll
                for (int j = 0; j < 4; j++) acc[i][j] += a[i] * b[j];
        }
        __syncthreads();
    }
#pragma unroll
    for (int i = 0; i < 4; i++) {
        int r = bm + ty + 16 * i;
#pragma unroll
        for (int j = 0; j < 4; j++) {
            int cidx = bn + tx + 16 * j;
            float bv = bias ? bias[cidx] : 0.f;
            C[r * N + cidx] = acc[i][j] + bv;
        }
    }
}

// ---------------------------------------------------------------------------
// lstm_two: 2 blocks (fwd, bwd), 512 threads, 1 block/CU.
//
// Empirical HW-budget law (rounds 0-2 counters): the allocator grants exactly
// file/(2 x WG_waves) VGPRs -- 128 @512thr, 64 @1024thr -- regardless of
// waves_per_eu or the LDS-forced 1-WG/CU limit. Full register residency of U
// (192 regs needed) is unwinnable; overflow values get remat'd AT USE and
// re-streamed from L2 latency-exposed (all three designs pinned at
// ~1170-1200us = per-CU L2 fill ceiling on ~370KB/step).
//
// This version is sized to the REAL budget (128):
//   kp [ 0, 36): LDS resident (147.5KB)           -- 36 kp
//   kp [36, 76): register resident, 80 VGPRs      -- 40 kp
//   kp [76,128): streamed from L2 each step as explicit source-level
//                coalesced uint2 loads in an unrolled loop -- the scheduler
//                hoists these with counted vmcnt (unlike remat'd loads),
//                so the 208KB/step stream runs at the ~64B/cyc/CU fill BW.
// Per-step: stream 3250cy (bound), VALU ~1100cy, DS ~1600cy (both hidden).
// ---------------------------------------------------------------------------
#define KLDS 36
#define KREG 40

// constant-index select across the five 8-wide vectors; folds at -O3
#define UA(r) ((r) < 8 ? qa0[(r) & 7] : (r) < 16 ? qa1[(r) & 7] : (r) < 24 ? qa2[(r) & 7] : \
               (r) < 32 ? qa3[(r) & 7] : qa4[(r) & 7])
#define UB(r) ((r) < 8 ? qb0[(r) & 7] : (r) < 16 ? qb1[(r) & 7] : (r) < 24 ? qb2[(r) & 7] : \
               (r) < 32 ? qb3[(r) & 7] : qb4[(r) & 7])

#define LOADQ(qi, va, vb)                                                     \
    do {                                                                      \
        _Pragma("unroll") for (int j = 0; j < 8; j++) {                       \
            uint2 w = *(const uint2*)&U[(KLDS + 8 * (qi) + j) * 1024 + 2 * t]; \
            va[j] = w.x;                                                      \
            vb[j] = w.y;                                                      \
        }                                                                     \
    } while (0)

__global__ __attribute__((amdgpu_flat_work_group_size(512, 512),
                          amdgpu_waves_per_eu(2, 2)))
void lstm_two(
        const unsigned int* __restrict__ Ua, const unsigned int* __restrict__ Ub,
        const float* __restrict__ Pa, const float* __restrict__ Pb,
        float* __restrict__ Oa, float* __restrict__ Ob) {
    const unsigned int* U = blockIdx.x ? Ub : Ua;
    const float* P = blockIdx.x ? Pb : Pa;
    float* O = blockIdx.x ? Ob : Oa;

    __shared__ unsigned int sU[KLDS * 1024];        // 147456 B, k-major
    __shared__ __align__(16) _Float16 sH[256];      // 512 B
    __shared__ float sZ[1024];                      // 4096 B

    int t = threadIdx.x;  // 0..511, owns columns 2t and 2t+1

    // stage LDS-resident k-pairs of U (k-major: sU[kp*1024 + col])
    for (int i = t; i < KLDS * 1024; i += 512) sU[i] = U[i];

    // register-resident k-pairs [KLDS, KLDS+40): 10 x 8-wide SSA vectors =
    // 80 VGPRs. 80 + ~24 working + ~24 in-flight loads fits the empirical
    // 128 budget -> no spill, no remat.
    u32x8 qa0, qa1, qa2, qa3, qa4;
    u32x8 qb0, qb1, qb2, qb3, qb4;
    LOADQ(0, qa0, qb0);
    LOADQ(1, qa1, qb1);
    LOADQ(2, qa2, qb2);
    LOADQ(3, qa3, qb3);
    LOADQ(4, qa4, qb4);

    // insurance: make the resident values opaque (non-rematerializable)
    asm volatile(""
                 : "+v"(qa0), "+v"(qa1), "+v"(qa2), "+v"(qa3), "+v"(qa4),
                   "+v"(qb0), "+v"(qb1), "+v"(qb2), "+v"(qb3), "+v"(qb4));

    float c = 0.f;
    if (t < 256) sH[t] = (_Float16)0.f;
    __syncthreads();

    const uint4* hp4 = (const uint4*)sH;  // 32 chunks x (4 h2v) = 256 h
    float2 pc = *(const float2*)(P + 2 * t);
    for (int step = 0; step < 512; step++) {
        float2 pn = pc;
        if (step < 511) pn = *(const float2*)(P + (step + 1) * 1024 + 2 * t);
        float acc0 = pc.x, acc1 = pc.y;  // two cols = two indep dep-chains

        // --- kp [0,36) from LDS: h via b128 broadcast, U via b64 (2-way=free)
#pragma unroll
        for (int cch = 0; cch < 9; cch++) {
            uint4 hc = hp4[cch];
            const unsigned int* su = &sU[(4 * cch) * 1024 + 2 * t];
            uint2 w;
            w = *(const uint2*)(su);
            acc0 = fdot2f(BC(hc.x), BC(w.x), acc0);
            acc1 = fdot2f(BC(hc.x), BC(w.y), acc1);
            w = *(const uint2*)(su + 1024);
            acc0 = fdot2f(BC(hc.y), BC(w.x), acc0);
            acc1 = fdot2f(BC(hc.y), BC(w.y), acc1);
            w = *(const uint2*)(su + 2048);
            acc0 = fdot2f(BC(hc.z), BC(w.x), acc0);
            acc1 = fdot2f(BC(hc.z), BC(w.y), acc1);
            w = *(const uint2*)(su + 3072);
            acc0 = fdot2f(BC(hc.w), BC(w.x), acc0);
            acc1 = fdot2f(BC(hc.w), BC(w.y), acc1);
        }
        // --- kp [36,76) from registers
#pragma unroll
        for (int cch = 9; cch < 19; cch++) {
            uint4 hc = hp4[cch];
            const int r0 = 4 * (cch - 9);
            acc0 = fdot2f(BC(hc.x), BC(UA(r0 + 0)), acc0);
            acc1 = fdot2f(BC(hc.x), BC(UB(r0 + 0)), acc1);
            acc0 = fdot2f(BC(hc.y), BC(UA(r0 + 1)), acc0);
            acc1 = fdot2f(BC(hc.y), BC(UB(r0 + 1)), acc1);
            acc0 = fdot2f(BC(hc.z), BC(UA(r0 + 2)), acc0);
            acc1 = fdot2f(BC(hc.z), BC(UB(r0 + 2)), acc1);
            acc0 = fdot2f(BC(hc.w), BC(UA(r0 + 3)), acc0);
            acc1 = fdot2f(BC(hc.w), BC(UB(r0 + 3)), acc1);
        }
        // --- kp [76,128) streamed from L2: explicit coalesced uint2 loads,
        // unrolled so the scheduler hoists them with counted vmcnt.
#pragma unroll
        for (int cch = 19; cch < 32; cch++) {
            uint4 hc = hp4[cch];
            const unsigned int* ug = &U[(4 * cch) * 1024 + 2 * t];
            uint2 w0 = *(const uint2*)(ug);
            uint2 w1 = *(const uint2*)(ug + 1024);
            uint2 w2 = *(const uint2*)(ug + 2048);
            uint2 w3 = *(const uint2*)(ug + 3072);
            acc0 = fdot2f(BC(hc.x), BC(w0.x), acc0);
            acc1 = fdot2f(BC(hc.x), BC(w0.y), acc1);
            acc0 = fdot2f(BC(hc.y), BC(w1.x), acc0);
            acc1 = fdot2f(BC(hc.y), BC(w1.y), acc1);
            acc0 = fdot2f(BC(hc.z), BC(w2.x), acc0);
            acc1 = fdot2f(BC(hc.z), BC(w2.y), acc1);
            acc0 = fdot2f(BC(hc.w), BC(w3.x), acc0);
            acc1 = fdot2f(BC(hc.w), BC(w3.y), acc1);
        }
        ((float2*)sZ)[t] = make_float2(acc0, acc1);
        __syncthreads();
        if (t < 256) {
            float zi = sZ[t], zf = sZ[256 + t], zg = sZ[512 + t], zo = sZ[768 + t];
            float ig = 1.f / (1.f + __expf(-zi));
            float fg = 1.f / (1.f + __expf(-zf));
            float gg = 1.f - 2.f / (1.f + __expf(2.f * zg));   // tanh
            float og = 1.f / (1.f + __expf(-zo));
            c = fg * c + ig * gg;
            float h = og * (1.f - 2.f / (1.f + __expf(2.f * c)));
            O[step * 256 + t] = h;
            sH[t] = (_Float16)h;
        }
        __syncthreads();
        pc = pn;
    }
}

// ---------------------------------------------------------------------------
// concat: V[t][0:256] = F[t], V[t][256:512] = Bk[511-t]
// ---------------------------------------------------------------------------
__global__ __launch_bounds__(256) void concat_k(const float* __restrict__ F,
                                                const float* __restrict__ Bk,
                                                float* __restrict__ V) {
    int idx = blockIdx.x * 256 + threadIdx.x;  // < 262144
    int t = idx >> 9, d = idx & 511;
    V[idx] = (d < 256) ? F[t * 256 + d] : Bk[(511 - t) * 256 + d - 256];
}

// ---------------------------------------------------------------------------
// head: S[i][j] = sum_h tanh(HF[i][h] + MF[j][h]) * w[h] + outBias
// ---------------------------------------------------------------------------
__global__ __launch_bounds__(256) void head_kernel(const float* __restrict__ HF,
                                                   const float* __restrict__ MF,
                                                   const float* __restrict__ w,
                                                   const float* __restrict__ outb,
                                                   float* __restrict__ S) {
    int i = blockIdx.x;
    __shared__ float sHF[512], sW[512];
    int tid = threadIdx.x;
    sHF[tid] = HF[i * 512 + tid];
    sHF[tid + 256] = HF[i * 512 + 256 + tid];
    sW[tid] = w[tid];
    sW[tid + 256] = w[tid + 256];
    __syncthreads();
    int lane = tid & 63, wv = tid >> 6;
    float ob = outb[0];
    for (int j = wv; j < 512; j += 4) {
        const float* mf = MF + j * 512;
        float acc = 0.f;
#pragma unroll
        for (int r = 0; r < 8; r++) {
            int h = lane + 64 * r;
            float x = sHF[h] + mf[h];
            acc += sW[h] * (1.f - 2.f / (1.f + __expf(2.f * x)));
        }
#pragma unroll
        for (int off = 32; off; off >>= 1) acc += __shfl_down(acc, off);
        if (lane == 0) S[i * 512 + j] = acc + ob;
    }
}

// ---------------------------------------------------------------------------
extern "C" void kernel_launch(void* const* d_in, const int* in_sizes, int n_in,
                              void* d_out, int out_size, void* d_ws, size_t ws_size,
                              hipStream_t stream) {
    const float* emb      = (const float*)d_in[0];
    const float* W_f1     = (const float*)d_in[1];
    const float* U_f1     = (const float*)d_in[2];
    const float* b_f1     = (const float*)d_in[3];
    const float* W_b1     = (const float*)d_in[4];
    const float* U_b1     = (const float*)d_in[5];
    const float* b_b1     = (const float*)d_in[6];
    const float* W_f2     = (const float*)d_in[7];
    const float* U_f2     = (const float*)d_in[8];
    const float* b_f2     = (const float*)d_in[9];
    const float* W_b2     = (const float*)d_in[10];
    const float* U_b2     = (const float*)d_in[11];
    const float* b_b2     = (const float*)d_in[12];
    const float* FOH      = (const float*)d_in[13];
    const float* FOM      = (const float*)d_in[14];
    const float* hidBias  = (const float*)d_in[15];
    const float* outLayer = (const float*)d_in[16];
    const float* outBias  = (const float*)d_in[17];
    float* out = (float*)d_out;

    // workspace carve (16 MB total)
    unsigned int* uf = (unsigned int*)d_ws;          // 4 x 131072 uints = 2MB
    unsigned int* uf_f1 = uf;
    unsigned int* uf_b1 = uf + 131072;
    unsigned int* uf_f2 = uf + 262144;
    unsigned int* uf_b2 = uf + 393216;
    float* f = (float*)d_ws + 524288;
    float* P1f = f;                 // 512x1024
    float* P1b = f + 524288;
    float* P2f = f + 1048576;
    float* P2b = f + 1572864;
    float* rf1 = f + 2097152;       // 512x256
    float* rb1 = f + 2228224;
    float* rf2 = f + 2359296;
    float* rb2 = f + 2490368;
    float* v    = f + 2621440;      // 512x512
    float* hcat = f + 2883584;
    float* HFb  = f + 3145728;      // 512x512 (includes hidBias)
    float* MFb  = f + 3407872;

    prep_u<<<512, 256, 0, stream>>>(U_f1, uf_f1);
    prep_u<<<512, 256, 0, stream>>>(U_b1, uf_b1);
    prep_u<<<512, 256, 0, stream>>>(U_f2, uf_f2);
    prep_u<<<512, 256, 0, stream>>>(U_b2, uf_b2);

    dim3 g1(1024 / 64, 512 / 64);
    gemm_bias<<<g1, 256, 0, stream>>>(emb, W_f1, b_f1, P1f, 512, 1024, 256, 0);
    gemm_bias<<<g1, 256, 0, stream>>>(emb, W_b1, b_b1, P1b, 512, 1024, 256, 1);

    lstm_two<<<2, 512, 0, stream>>>(uf_f1, uf_b1, P1f, P1b, rf1, rb1);

    concat_k<<<1024, 256, 0, stream>>>(rf1, rb1, v);

    gemm_bias<<<g1, 256, 0, stream>>>(v, W_f2, b_f2, P2f, 512, 1024, 512, 0);
    gemm_bias<<<g1, 256, 0, stream>>>(v, W_b2, b_b2, P2b, 512, 1024, 512, 1);

    lstm_two<<<2, 512, 0, stream>>>(uf_f2, uf_b2, P2f, P2b, rf2, rb2);

    concat_k<<<1024, 256, 0, stream>>>(rf2, rb2, hcat);

    dim3 g2(512 / 64, 512 / 64);
    gemm_bias<<<g2, 256, 0, stream>>>(hcat, FOH, hidBias, HFb, 512, 512, 512, 0);
    gemm_bias<<<g2, 256, 0, stream>>>(hcat, FOM, nullptr, MFb, 512, 512, 512, 0);

    head_kernel<<<512, 256, 0, stream>>>(HFb, MFb, outLayer, outBias, out);
}